// Round 3
// baseline (7953.043 us; speedup 1.0000x reference)
//
#include <hip/hip_runtime.h>
#include <hip/hip_cooperative_groups.h>
#include <stdint.h>

namespace cg = cooperative_groups;

// Problem constants
#define BB   64
#define TTT  250
#define INN  1024
#define HIDD 2048
#define OUTT 256

#define DECAYF 0.951229424500714f   // exp(-1/20)
#define ALPHAF 0.951229424500714f
#define LRF    1e-4f
#define WDF    0.01f
#define SCLF   0.2f

// d_out offsets (float elements)
#define O_L1SEQ 0
#define O_L2SEQ 32768000
#define O_V1    36864000
#define O_V2    36995072
#define O_L1TR  37011456
#define O_L2TR  37142528

// ws layout (byte offsets). 4-slot rotating staging buffers (~3 MB total).
// ALL of these are accessed exclusively via relaxed agent-scope (sc1) atomics.
#define WS_XB    0          // bf16 [4][64][1024]  x_t as bf16 (A-op for gemm1)
#define WS_INTRT 524288     // bf16 [4][1024][64]  in_tr transposed (B-op for w_in update)
#define WS_L1B   1048576    // bf16 [4][64][2048]  l1 spikes (A-op for gemm2)
#define WS_L1TT  2097152    // bf16 [4][2048][64]  l1_tr transposed (B-op for w_hid update)
#define WS_FLAG  3145728    // int f_prep[256] f_l1done[256] f_l1step[256] f_l2done[256]

#define NB1 64     // layer-1 blocks: 32 h each, w_in slice resident
#define NB2 16     // layer-2 blocks: 16 o each, w_hid slice resident
#define NBLK 80
#define NTHR 512   // 8 waves

typedef __attribute__((ext_vector_type(8))) short short8v;
typedef __attribute__((ext_vector_type(4))) float float4v;
typedef unsigned long long u64;

__device__ inline short f2bf(float f) {
  union { float f; uint32_t u; } c; c.f = f;
  uint32_t u = c.u + 0x7fffu + ((c.u >> 16) & 1u);  // RNE
  return (short)(u >> 16);
}

// ---- coherent (sc1, L2-bypass) staging access: relaxed agent atomics ----
// No acquire/release anywhere: __syncthreads()'s mandatory vmcnt(0) drain
// before s_barrier provides the store->flag ordering; sc1 loads can't see
// stale cache because they bypass L1/L2 entirely.
__device__ inline void st8c(short* p, u64 v) {
  __hip_atomic_store((u64*)p, v, __ATOMIC_RELAXED, __HIP_MEMORY_SCOPE_AGENT);
}
__device__ inline short8v ld16c(const short* p) {
  union { u64 q[2]; short8v v; } u;
  u.q[0] = __hip_atomic_load((u64*)p, __ATOMIC_RELAXED, __HIP_MEMORY_SCOPE_AGENT);
  u.q[1] = __hip_atomic_load((u64*)(p + 4), __ATOMIC_RELAXED, __HIP_MEMORY_SCOPE_AGENT);
  return u.v;
}
__device__ inline u64 pack4(short a, short b, short c, short d) {
  union { short s[4]; u64 q; } u; u.s[0] = a; u.s[1] = b; u.s[2] = c; u.s[3] = d;
  return u.q;
}
__device__ inline int ldf(int* p) {
  return __hip_atomic_load(p, __ATOMIC_RELAXED, __HIP_MEMORY_SCOPE_AGENT);
}
__device__ inline void postflag(int* p) {
  __hip_atomic_fetch_add(p, 1, __ATOMIC_RELAXED, __HIP_MEMORY_SCOPE_AGENT);
}

// XOR swizzles for LDS operands: 16 B chunks XOR'd with (row&7)
__device__ inline int swz1024(int row, int k) {
  return row * 1024 + ((((k) >> 3) ^ (row & 7)) << 3) + ((k) & 7);
}
__device__ inline int swz2048(int row, int k) {
  return row * 2048 + ((((k) >> 3) ^ (row & 7)) << 3) + ((k) & 7);
}
__device__ inline int swz64(int row, int k) {
  return row * 64 + ((((k) >> 3) ^ (row & 7)) << 3) + ((k) & 7);
}

struct SG1 {                 // layer-1 block LDS (91136 B)
  short winb[32 * 1024];     // bf16 shadow of w_in slice, swizzled
  float v1s[64 * 33];        // v1 state, padded
  float l1trs[64 * 33];      // l1_tr f32 state, padded
  short l1trT[32 * 64];      // l1_tr^T bf16 (A-op for w_in update), swizzled
  short zsc[64 * 36];        // z bounce buffer for packed l1 publish
};
struct SG2 {                 // layer-2 block LDS (80384 B)
  short whb[16 * 2048];      // bf16 shadow of w_hid slice, swizzled
  float v2s[64 * 17];
  float l2trs[64 * 17];
  short l2trT[16 * 64];      // swizzled
  float red[4 * 256];        // K-split reduce scratch
};

__global__ __launch_bounds__(NTHR, 2) void kmain(const float* __restrict__ x,
                                                 const float* __restrict__ w_in,
                                                 const float* __restrict__ w_hid,
                                                 float* __restrict__ out,
                                                 char* __restrict__ ws) {
  __shared__ __align__(16) char smem[91136];
  cg::grid_group grid = cg::this_grid();
  const int bid = blockIdx.x, tid = threadIdx.x;
  const int lane = tid & 63, wv = tid >> 6;
  const int mr = lane & 15, q = lane >> 4;

  int* FB = (int*)(ws + WS_FLAG);
  int* FP = FB;          // f_prep[s]  : 64 posts when xb/intrT for step s written
  int* FD = FB + 256;    // f_l1done[s]: 64 posts when l1bg/l1tt slot s written
  int* FS = FB + 512;    // f_l1step[s]: 64 posts when L1 done reading step-s prep bufs
  int* FL2 = FB + 768;   // f_l2done[s]: 16 posts when L2 done reading step-s buffers

  // zero flags; the one cooperative sync publishes them (grid.sync fences)
  if (bid == 0) for (int c = tid; c < 1024; c += NTHR) FB[c] = 0;
  grid.sync();

  if (bid < NB1) {
    // ---------------- layer-1 block: owns w_in rows [h0, h0+32) ----------------
    SG1& S = *(SG1*)smem;
    const int h0 = bid * 32;
    const int bt = wv & 3, ht = wv >> 2;   // wave tile: b-tile, h-tile
    float wreg[64];                        // f32 w_in master
    float itr[4] = {0.f, 0.f, 0.f, 0.f};   // in_tr state (intrT-half threads only)

    // prologue: load w_in slice -> regs + bf16 LDS shadow
#pragma unroll
    for (int j = 0; j < 16; j++) {
      const int it = (wv & 3) * 16 + j;
      const int i = it * 16 + mr;
#pragma unroll
      for (int r = 0; r < 4; r++) {
        const int hl = ht * 16 + q * 4 + r;
        float w = w_in[(h0 + hl) * INN + i];
        wreg[j * 4 + r] = w;
        S.winb[swz1024(hl, i)] = f2bf(w);
      }
    }
    for (int c = tid; c < 64 * 33; c += NTHR) { S.v1s[c] = 0.f; S.l1trs[c] = 0.f; }
    // prep step 0 into slot 0. Split-half: tid<256 -> xb rows, tid>=256 -> intrT cols.
    if (tid < 256) {
      const int gg = bid * 256 + tid;                 // [0,16384)
      const int b = gg >> 8, i0 = (gg & 255) * 4;
      float4 xv = *(const float4*)(x + (b * TTT + 0) * INN + i0);
      st8c((short*)(ws + WS_XB) + b * INN + i0,
           pack4(f2bf(xv.x), f2bf(xv.y), f2bf(xv.z), f2bf(xv.w)));
    } else {
      const int gg = bid * 256 + (tid - 256);
      const int i = gg >> 4, b0 = (gg & 15) * 4;
#pragma unroll
      for (int j = 0; j < 4; j++)
        itr[j] = (1.f - DECAYF) * x[((b0 + j) * TTT + 0) * INN + i];
      st8c((short*)(ws + WS_INTRT) + i * 64 + b0,
           pack4(f2bf(itr[0]), f2bf(itr[1]), f2bf(itr[2]), f2bf(itr[3])));
    }
    __syncthreads();             // drains sc1 stores (vmcnt(0) before s_barrier)
    if (tid == 0) postflag(&FP[0]);

    for (int t = 0; t < TTT; t++) {
      const int sl = t & 3;
      // waits: prep(t) ready; prep slot (t+1)&3 free; l1 slot t&3 free
      if (tid == 0) {
        for (;;) {
          int a = ldf(&FP[t]);
          int b2 = (t >= 3) ? ldf(&FS[t - 3]) : 64;
          int c2 = (t >= 4) ? ldf(&FL2[t - 4]) : 16;
          if (a >= 64 && b2 >= 64 && c2 >= 16) break;
          __builtin_amdgcn_s_sleep(1);
        }
      }
      __syncthreads();

      // ---- prep(t+1), early (slack on the all-L1 exchange) ----
      if (t + 1 < TTT) {
        const int sn = (t + 1) & 3;
        if (tid < 256) {
          const int gg = bid * 256 + tid;
          const int b = gg >> 8, i0 = (gg & 255) * 4;
          float4 xv = *(const float4*)(x + (b * TTT + (t + 1)) * INN + i0);
          st8c((short*)(ws + WS_XB) + sn * (BB * INN) + b * INN + i0,
               pack4(f2bf(xv.x), f2bf(xv.y), f2bf(xv.z), f2bf(xv.w)));
        } else {
          const int gg = bid * 256 + (tid - 256);
          const int i = gg >> 4, b0 = (gg & 15) * 4;
#pragma unroll
          for (int j = 0; j < 4; j++) {
            float xs = x[((b0 + j) * TTT + (t + 1)) * INN + i];
            itr[j] = DECAYF * itr[j] + (1.f - DECAYF) * xs;
          }
          st8c((short*)(ws + WS_INTRT) + sn * (INN * BB) + i * 64 + b0,
               pack4(f2bf(itr[0]), f2bf(itr[1]), f2bf(itr[2]), f2bf(itr[3])));
        }
        __syncthreads();         // drain, then relaxed post is safe
        if (tid == 0) postflag(&FP[t + 1]);
      }

      // ---- gemm1(t): cur1[64b x 32h] = x_t @ w_in^T, K=1024 ----
      const short* xb = (const short*)(ws + WS_XB) + sl * (BB * INN);
      float4v acc = {0.f, 0.f, 0.f, 0.f};
      {
        const short* xrow = xb + (bt * 16 + mr) * INN;
        const int brow = ht * 16 + mr;
#pragma unroll 8
        for (int ks = 0; ks < 32; ks++) {
          const int koff = ks * 32 + q * 8;
          short8v af = ld16c(xrow + koff);
          short8v bf = *(const short8v*)&S.winb[swz1024(brow, koff)];
          acc = __builtin_amdgcn_mfma_f32_16x16x32_bf16(af, bf, acc, 0, 0, 0);
        }
      }
      // ---- LIF1 + trace; packed publish of l1_tr^T; z staged to LDS ----
      short* l1bg = (short*)(ws + WS_L1B) + sl * (BB * HIDD);
      short* l1ttg = (short*)(ws + WS_L1TT) + sl * (HIDD * BB);
      {
        const int hl = ht * 16 + mr, h = h0 + hl;
        const int b0 = bt * 16 + q * 4;
        short trs[4];
#pragma unroll
        for (int r = 0; r < 4; r++) {
          const int b = b0 + r;
          float v = ALPHAF * S.v1s[b * 33 + hl] + SCLF * acc[r];
          float z = v > 1.0f ? 1.0f : 0.0f;
          v -= z;
          S.v1s[b * 33 + hl] = v;
          out[O_L1SEQ + (b * TTT + t) * HIDD + h] = z;
          S.zsc[b * 36 + hl] = f2bf(z);
          float tr = DECAYF * S.l1trs[b * 33 + hl] + (1.f - DECAYF) * z;
          S.l1trs[b * 33 + hl] = tr;
          short tb = f2bf(tr);
          S.l1trT[swz64(hl, b)] = tb;
          trs[r] = tb;
        }
        st8c(l1ttg + h * 64 + b0, pack4(trs[0], trs[1], trs[2], trs[3]));
      }
      __syncthreads();           // zsc/l1trT visible in LDS
      // packed l1 publish: thread -> (b, h-quad), one 8B coherent store
      {
        const int b = tid >> 3, hq = tid & 7;
        short4 zz = *(const short4*)&S.zsc[b * 36 + hq * 4];
        st8c(l1bg + b * HIDD + h0 + hq * 4, pack4(zz.x, zz.y, zz.z, zz.w));
      }
      __syncthreads();           // drain l1bg/l1ttg sc1 stores
      if (tid == 0) postflag(&FD[t]);

      // ---- w_in update: D[32h x 1024i] = l1_tr^T @ in_tr, K=64 ----
      {
        const short* intT = (const short*)(ws + WS_INTRT) + sl * (INN * BB);
        const int arow = ht * 16 + mr;
#pragma unroll
        for (int j = 0; j < 16; j++) {
          const int it = (wv & 3) * 16 + j;
          float4v a2 = {0.f, 0.f, 0.f, 0.f};
#pragma unroll
          for (int ks = 0; ks < 2; ks++) {
            const int koff = ks * 32 + q * 8;
            short8v af = *(const short8v*)&S.l1trT[swz64(arow, koff)];
            short8v bf = ld16c(intT + (it * 16 + mr) * 64 + koff);
            a2 = __builtin_amdgcn_mfma_f32_16x16x32_bf16(af, bf, a2, 0, 0, 0);
          }
          const int i = it * 16 + mr;
#pragma unroll
          for (int r = 0; r < 4; r++) {
            const int hl = ht * 16 + q * 4 + r;
            float w = wreg[j * 4 + r] * (1.f - LRF * WDF) + (LRF / 64.f) * a2[r];
            wreg[j * 4 + r] = w;
            S.winb[swz1024(hl, i)] = f2bf(w);
          }
        }
      }
      __syncthreads();           // all reads of step-t prep buffers done
      if (tid == 0) postflag(&FS[t]);
    }
    // epilogue: flush v1 / l1_tr
    for (int c = tid; c < 64 * 32; c += NTHR) {
      const int b = c >> 5, hl = c & 31;
      out[O_V1 + b * HIDD + h0 + hl] = S.v1s[b * 33 + hl];
      out[O_L1TR + b * HIDD + h0 + hl] = S.l1trs[b * 33 + hl];
    }
  } else {
    // ---------------- layer-2 block: owns w_hid rows [o0, o0+16) ----------------
    SG2& S = *(SG2*)smem;
    const int o0 = (bid - NB1) * 16;
    const int bt = wv & 3, kh = wv >> 2;   // b-tile, K-half
    float wreg[64];                        // f32 w_hid master

#pragma unroll
    for (int j = 0; j < 16; j++) {
      const int hcol = (wv * 16 + j) * 16 + mr;
#pragma unroll
      for (int r = 0; r < 4; r++) {
        const int ol = q * 4 + r;
        float w = w_hid[(o0 + ol) * HIDD + hcol];
        wreg[j * 4 + r] = w;
        S.whb[swz2048(ol, hcol)] = f2bf(w);
      }
    }
    for (int c = tid; c < 64 * 17; c += NTHR) { S.v2s[c] = 0.f; S.l2trs[c] = 0.f; }

    for (int u = 0; u < TTT; u++) {
      const int sl = u & 3;
      if (tid == 0) {
        while (ldf(&FD[u]) < 64) __builtin_amdgcn_s_sleep(1);
      }
      __syncthreads();

      const short* l1bg = (const short*)(ws + WS_L1B) + sl * (BB * HIDD);
      // gemm2: cur2[64b x 16o] = l1 @ w_hid^T, K=2048 split 2 ways across waves
      float4v acc = {0.f, 0.f, 0.f, 0.f};
      {
        const short* arow = l1bg + (bt * 16 + mr) * HIDD + kh * 1024;
#pragma unroll 8
        for (int ks = 0; ks < 32; ks++) {
          const int kk = kh * 1024 + ks * 32 + q * 8;
          short8v af = ld16c(arow + ks * 32 + q * 8);
          short8v bf = *(const short8v*)&S.whb[swz2048(mr, kk)];
          acc = __builtin_amdgcn_mfma_f32_16x16x32_bf16(af, bf, acc, 0, 0, 0);
        }
      }
      if (kh == 1) { *(float4v*)&S.red[bt * 256 + lane * 4] = acc; }
      __syncthreads();
      if (kh == 0) {
        float4v o4 = *(const float4v*)&S.red[bt * 256 + lane * 4];
#pragma unroll
        for (int r = 0; r < 4; r++) {
          const int b = bt * 16 + q * 4 + r;
          float v = ALPHAF * S.v2s[b * 17 + mr] + SCLF * (acc[r] + o4[r]);
          float z = v > 1.0f ? 1.0f : 0.0f;
          v -= z;
          S.v2s[b * 17 + mr] = v;
          out[O_L2SEQ + (b * TTT + u) * OUTT + o0 + mr] = z;
          float tr = DECAYF * S.l2trs[b * 17 + mr] + (1.f - DECAYF) * z;
          S.l2trs[b * 17 + mr] = tr;
          S.l2trT[swz64(mr, b)] = f2bf(tr);
        }
      }
      __syncthreads();   // l2trT ready; whb reads done before update writes

      // w_hid update: D[16o x 2048h] = l2_tr^T @ l1_tr, K=64
      {
        const short* l1ttg = (const short*)(ws + WS_L1TT) + sl * (HIDD * BB);
#pragma unroll
        for (int j = 0; j < 16; j++) {
          const int htile = wv * 16 + j;
          float4v a2 = {0.f, 0.f, 0.f, 0.f};
#pragma unroll
          for (int ks = 0; ks < 2; ks++) {
            const int koff = ks * 32 + q * 8;
            short8v af = *(const short8v*)&S.l2trT[swz64(mr, koff)];
            short8v bf = ld16c(l1ttg + (htile * 16 + mr) * 64 + koff);
            a2 = __builtin_amdgcn_mfma_f32_16x16x32_bf16(af, bf, a2, 0, 0, 0);
          }
          const int hcol = htile * 16 + mr;
#pragma unroll
          for (int r = 0; r < 4; r++) {
            const int ol = q * 4 + r;
            float w = wreg[j * 4 + r] * (1.f - LRF * WDF) + (LRF / 64.f) * a2[r];
            wreg[j * 4 + r] = w;
            S.whb[swz2048(ol, hcol)] = f2bf(w);
          }
        }
      }
      __syncthreads();   // all reads of step-u buffers done
      if (tid == 0) postflag(&FL2[u]);
    }
    for (int c = tid; c < 64 * 16; c += NTHR) {
      const int b = c >> 4, ol = c & 15;
      out[O_V2 + b * OUTT + o0 + ol] = S.v2s[b * 17 + ol];
      out[O_L2TR + b * OUTT + o0 + ol] = S.l2trs[b * 17 + ol];
    }
  }
}

extern "C" void kernel_launch(void* const* d_in, const int* in_sizes, int n_in,
                              void* d_out, int out_size, void* d_ws, size_t ws_size,
                              hipStream_t stream) {
  const float* x = (const float*)d_in[0];
  const float* w_in = (const float*)d_in[1];
  const float* w_hid = (const float*)d_in[2];
  float* out = (float*)d_out;
  char* ws = (char*)d_ws;

  void* args[] = {(void*)&x, (void*)&w_in, (void*)&w_hid, (void*)&out, (void*)&ws};
  hipLaunchCooperativeKernel(reinterpret_cast<void*>(kmain), dim3(NBLK), dim3(NTHR),
                             args, 0, stream);
}

// Round 4
// 4523.434 us; speedup vs baseline: 1.7582x; 1.7582x over previous
//
#include <hip/hip_runtime.h>
#include <hip/hip_cooperative_groups.h>
#include <stdint.h>

namespace cg = cooperative_groups;

// Problem constants
#define BB   64
#define TTT  250
#define INN  1024
#define HIDD 2048
#define OUTT 256

#define DECAYF 0.951229424500714f   // exp(-1/20)
#define ALPHAF 0.951229424500714f
#define LRF    1e-4f
#define WDF    0.01f
#define SCLF   0.2f

// d_out offsets (float elements)
#define O_L1SEQ 0
#define O_L2SEQ 32768000
#define O_V1    36864000
#define O_V2    36995072
#define O_L1TR  37011456
#define O_L2TR  37142528

// Chunking: CH timesteps per sync phase. Sync cost (wbl2/inv fences, straggler
// barrier, LLC flag latency) is per-phase -> amortized /CH.
#define CH  3
#define NPH 84              // ceil(250/3); last phase has 1 step

// ws layout (byte offsets), ~5.5 MB. Plain cached access everywhere.
// xb/intrT: 3-phase parity (one-phase slack on the all-L1 prep exchange).
// l1b/l1tt: 2-phase parity (L2 lags one phase).
#define WS_XB    0          // bf16 [3][CH][64][1024]
#define WS_INTRT 1179648    // bf16 [3][CH][1024][64]
#define WS_L1B   2359296    // bf16 [2][CH][64][2048]
#define WS_L1TT  3932160    // bf16 [2][CH][2048][64]
#define WS_FLAG  5505024    // int FP[128] FE[128] FL2[128]

#define NB1 64     // layer-1 blocks: 32 h each, w_in slice resident
#define NB2 16     // layer-2 blocks: 16 o each, w_hid slice resident
#define NBLK 80
#define NTHR 512   // 8 waves

typedef __attribute__((ext_vector_type(8))) short short8v;
typedef __attribute__((ext_vector_type(4))) float float4v;

__device__ inline short f2bf(float f) {
  union { float f; uint32_t u; } c; c.f = f;
  uint32_t u = c.u + 0x7fffu + ((c.u >> 16) & 1u);  // RNE
  return (short)(u >> 16);
}

// flag primitives: R2-proven release posts + relaxed spin + threadfence acquire
__device__ inline int ldf(int* p) {
  return __hip_atomic_load(p, __ATOMIC_RELAXED, __HIP_MEMORY_SCOPE_AGENT);
}
__device__ inline void postflag(int* p) {
  __hip_atomic_fetch_add(p, 1, __ATOMIC_RELEASE, __HIP_MEMORY_SCOPE_AGENT);
}

// XOR swizzles for LDS operands: 16 B chunks XOR'd with (row&7)
__device__ inline int swz1024(int row, int k) {
  return row * 1024 + ((((k) >> 3) ^ (row & 7)) << 3) + ((k) & 7);
}
__device__ inline int swz2048(int row, int k) {
  return row * 2048 + ((((k) >> 3) ^ (row & 7)) << 3) + ((k) & 7);
}
__device__ inline int swz64(int row, int k) {
  return row * 64 + ((((k) >> 3) ^ (row & 7)) << 3) + ((k) & 7);
}

struct SG1 {                 // layer-1 block LDS (86528 B)
  short winb[32 * 1024];     // bf16 shadow of w_in slice, swizzled
  float v1s[64 * 33];        // v1 state, padded
  float l1trs[64 * 33];      // l1_tr f32 state, padded
  short l1trT[32 * 64];      // l1_tr^T bf16 (A-op for w_in update), swizzled
};
struct SG2 {                 // layer-2 block LDS (80384 B)
  short whb[16 * 2048];      // bf16 shadow of w_hid slice, swizzled
  float v2s[64 * 17];
  float l2trs[64 * 17];
  short l2trT[16 * 64];      // swizzled
  float red[4 * 256];        // K-split reduce scratch
};

__global__ __launch_bounds__(NTHR, 2) void kmain(const float* __restrict__ x,
                                                 const float* __restrict__ w_in,
                                                 const float* __restrict__ w_hid,
                                                 float* __restrict__ out,
                                                 char* __restrict__ ws) {
  __shared__ __align__(16) char smem[86528];
  cg::grid_group grid = cg::this_grid();
  const int bid = blockIdx.x, tid = threadIdx.x;
  const int lane = tid & 63, wv = tid >> 6;
  const int mr = lane & 15, q = lane >> 4;

  int* FB = (int*)(ws + WS_FLAG);
  int* FP = FB;          // FP[p] : 64 posts when xb/intrT for phase p staged
  int* FE = FB + 128;    // FE[p] : 64 posts when L1 phase p fully done
  int* FL2 = FB + 256;   // FL2[p]: 16 posts when L2 done reading phase-p buffers

  if (bid == 0) for (int c = tid; c < 384; c += NTHR) FB[c] = 0;
  grid.sync();

  if (bid < NB1) {
    // ---------------- layer-1 block: owns w_in rows [h0, h0+32) ----------------
    SG1& S = *(SG1*)smem;
    const int h0 = bid * 32;
    const int bt = wv & 3, ht = wv >> 2;   // wave tile: b-tile, h-tile
    float wreg[64];                        // f32 w_in master
    float itr[4] = {0.f, 0.f, 0.f, 0.f};   // in_tr state (intrT-half threads)

    // prologue: load w_in slice -> regs + bf16 LDS shadow
#pragma unroll
    for (int j = 0; j < 16; j++) {
      const int it = (wv & 3) * 16 + j;
      const int i = it * 16 + mr;
#pragma unroll
      for (int r = 0; r < 4; r++) {
        const int hl = ht * 16 + q * 4 + r;
        float w = w_in[(h0 + hl) * INN + i];
        wreg[j * 4 + r] = w;
        S.winb[swz1024(hl, i)] = f2bf(w);
      }
    }
    for (int c = tid; c < 64 * 33; c += NTHR) { S.v1s[c] = 0.f; S.l1trs[c] = 0.f; }
    // prologue prep: stage phase 0 (steps 0..2) into parity 0
    if (tid < 256) {
      const int gg = bid * 256 + tid;
      const int b = gg >> 8, i0 = (gg & 255) * 4;
      for (int s = 0; s < CH; s++) {
        float4 xv = *(const float4*)(x + (b * TTT + s) * INN + i0);
        short4 s4; s4.x = f2bf(xv.x); s4.y = f2bf(xv.y); s4.z = f2bf(xv.z); s4.w = f2bf(xv.w);
        *(short4*)((short*)(ws + WS_XB) + s * (BB * INN) + b * INN + i0) = s4;
      }
    } else {
      const int gg = bid * 256 + (tid - 256);
      const int i = gg >> 4, b0 = (gg & 15) * 4;
      for (int s = 0; s < CH; s++) {
#pragma unroll
        for (int j = 0; j < 4; j++) {
          float xs = x[((b0 + j) * TTT + s) * INN + i];
          itr[j] = DECAYF * itr[j] + (1.f - DECAYF) * xs;
        }
        short4 s4; s4.x = f2bf(itr[0]); s4.y = f2bf(itr[1]); s4.z = f2bf(itr[2]); s4.w = f2bf(itr[3]);
        *(short4*)((short*)(ws + WS_INTRT) + s * (INN * BB) + i * 64 + b0) = s4;
      }
    }
    __syncthreads();
    if (tid == 0) postflag(&FP[0]);

    for (int p = 0; p < NPH; p++) {
      const int t0 = p * CH;
      const int ns = (TTT - t0 < CH) ? (TTT - t0) : CH;
      // phase-start wait: prep(p) staged; parity-3 prep slots free; l1 slots free
      if (tid == 0) {
        for (;;) {
          int a = ldf(&FP[p]);
          int b2 = (p >= 2) ? ldf(&FE[p - 2]) : 64;
          int c2 = (p >= 2) ? ldf(&FL2[p - 2]) : 16;
          if (a >= 64 && b2 >= 64 && c2 >= 16) break;
        }
        __threadfence();
      }
      __syncthreads();

      // ---- prep(p+1), early: full-phase slack on the all-L1 exchange ----
      if (p + 1 < NPH) {
        const int pt0 = (p + 1) * CH, pp = (p + 1) % 3;
        if (tid < 256) {
          const int gg = bid * 256 + tid;
          const int b = gg >> 8, i0 = (gg & 255) * 4;
          for (int s = 0; s < CH && pt0 + s < TTT; s++) {
            float4 xv = *(const float4*)(x + (b * TTT + pt0 + s) * INN + i0);
            short4 s4; s4.x = f2bf(xv.x); s4.y = f2bf(xv.y); s4.z = f2bf(xv.z); s4.w = f2bf(xv.w);
            *(short4*)((short*)(ws + WS_XB) + (pp * CH + s) * (BB * INN) + b * INN + i0) = s4;
          }
        } else {
          const int gg = bid * 256 + (tid - 256);
          const int i = gg >> 4, b0 = (gg & 15) * 4;
          for (int s = 0; s < CH && pt0 + s < TTT; s++) {
#pragma unroll
            for (int j = 0; j < 4; j++) {
              float xs = x[((b0 + j) * TTT + pt0 + s) * INN + i];
              itr[j] = DECAYF * itr[j] + (1.f - DECAYF) * xs;
            }
            short4 s4; s4.x = f2bf(itr[0]); s4.y = f2bf(itr[1]); s4.z = f2bf(itr[2]); s4.w = f2bf(itr[3]);
            *(short4*)((short*)(ws + WS_INTRT) + (pp * CH + s) * (INN * BB) + i * 64 + b0) = s4;
          }
        }
        __syncthreads();
        if (tid == 0) postflag(&FP[p + 1]);
      }

      // ---- CH local steps: gemm1 -> LIF1 -> publish -> w_in update ----
      for (int s = 0; s < ns; s++) {
        const int t = t0 + s;
        const short* xb = (const short*)(ws + WS_XB) + ((p % 3) * CH + s) * (BB * INN);
        float4v acc = {0.f, 0.f, 0.f, 0.f};
        {
          const short* xrow = xb + (bt * 16 + mr) * INN;
          const int brow = ht * 16 + mr;
#pragma unroll 8
          for (int ks = 0; ks < 32; ks++) {
            const int koff = ks * 32 + q * 8;
            short8v af = *(const short8v*)(xrow + koff);
            short8v bf = *(const short8v*)&S.winb[swz1024(brow, koff)];
            acc = __builtin_amdgcn_mfma_f32_16x16x32_bf16(af, bf, acc, 0, 0, 0);
          }
        }
        short* l1bg = (short*)(ws + WS_L1B) + ((p & 1) * CH + s) * (BB * HIDD);
        short* l1ttg = (short*)(ws + WS_L1TT) + ((p & 1) * CH + s) * (HIDD * BB);
        {
          const int hl = ht * 16 + mr, h = h0 + hl;
          const int b0 = bt * 16 + q * 4;
          short trs[4];
#pragma unroll
          for (int r = 0; r < 4; r++) {
            const int b = b0 + r;
            float v = ALPHAF * S.v1s[b * 33 + hl] + SCLF * acc[r];
            float z = v > 1.0f ? 1.0f : 0.0f;
            v -= z;
            S.v1s[b * 33 + hl] = v;
            out[O_L1SEQ + (b * TTT + t) * HIDD + h] = z;
            l1bg[b * HIDD + h] = f2bf(z);
            float tr = DECAYF * S.l1trs[b * 33 + hl] + (1.f - DECAYF) * z;
            S.l1trs[b * 33 + hl] = tr;
            short tb = f2bf(tr);
            S.l1trT[swz64(hl, b)] = tb;
            trs[r] = tb;
          }
          *(short4*)(l1ttg + h * 64 + b0) = *(short4*)trs;
        }
        __syncthreads();   // l1trT complete; winb reads done before update writes
        {
          const short* intT = (const short*)(ws + WS_INTRT) + ((p % 3) * CH + s) * (INN * BB);
          const int arow = ht * 16 + mr;
#pragma unroll
          for (int j = 0; j < 16; j++) {
            const int it = (wv & 3) * 16 + j;
            float4v a2 = {0.f, 0.f, 0.f, 0.f};
#pragma unroll
            for (int ks = 0; ks < 2; ks++) {
              const int koff = ks * 32 + q * 8;
              short8v af = *(const short8v*)&S.l1trT[swz64(arow, koff)];
              short8v bf = *(const short8v*)(intT + (it * 16 + mr) * 64 + koff);
              a2 = __builtin_amdgcn_mfma_f32_16x16x32_bf16(af, bf, a2, 0, 0, 0);
            }
            const int i = it * 16 + mr;
#pragma unroll
            for (int r = 0; r < 4; r++) {
              const int hl = ht * 16 + q * 4 + r;
              float w = wreg[j * 4 + r] * (1.f - LRF * WDF) + (LRF / 64.f) * a2[r];
              wreg[j * 4 + r] = w;
              S.winb[swz1024(hl, i)] = f2bf(w);
            }
          }
        }
        __syncthreads();   // winb consistent before next step's gemm1
      }
      if (tid == 0) postflag(&FE[p]);   // covers l1 publishes + prep-slot reads
    }
    // epilogue: flush v1 / l1_tr
    for (int c = tid; c < 64 * 32; c += NTHR) {
      const int b = c >> 5, hl = c & 31;
      out[O_V1 + b * HIDD + h0 + hl] = S.v1s[b * 33 + hl];
      out[O_L1TR + b * HIDD + h0 + hl] = S.l1trs[b * 33 + hl];
    }
  } else {
    // ---------------- layer-2 block: owns w_hid rows [o0, o0+16) ----------------
    SG2& S = *(SG2*)smem;
    const int o0 = (bid - NB1) * 16;
    const int bt = wv & 3, kh = wv >> 2;   // b-tile, K-half
    float wreg[64];                        // f32 w_hid master

#pragma unroll
    for (int j = 0; j < 16; j++) {
      const int hcol = (wv * 16 + j) * 16 + mr;
#pragma unroll
      for (int r = 0; r < 4; r++) {
        const int ol = q * 4 + r;
        float w = w_hid[(o0 + ol) * HIDD + hcol];
        wreg[j * 4 + r] = w;
        S.whb[swz2048(ol, hcol)] = f2bf(w);
      }
    }
    for (int c = tid; c < 64 * 17; c += NTHR) { S.v2s[c] = 0.f; S.l2trs[c] = 0.f; }

    for (int p = 0; p < NPH; p++) {
      const int t0 = p * CH;
      const int ns = (TTT - t0 < CH) ? (TTT - t0) : CH;
      if (tid == 0) {
        while (ldf(&FE[p]) < 64) {}
        __threadfence();
      }
      __syncthreads();

      for (int s = 0; s < ns; s++) {
        const int u = t0 + s;
        const short* l1bg = (const short*)(ws + WS_L1B) + ((p & 1) * CH + s) * (BB * HIDD);
        float4v acc = {0.f, 0.f, 0.f, 0.f};
        {
          const short* arow = l1bg + (bt * 16 + mr) * HIDD + kh * 1024;
#pragma unroll 8
          for (int ks = 0; ks < 32; ks++) {
            const int kk = kh * 1024 + ks * 32 + q * 8;
            short8v af = *(const short8v*)(arow + ks * 32 + q * 8);
            short8v bf = *(const short8v*)&S.whb[swz2048(mr, kk)];
            acc = __builtin_amdgcn_mfma_f32_16x16x32_bf16(af, bf, acc, 0, 0, 0);
          }
        }
        if (kh == 1) { *(float4v*)&S.red[bt * 256 + lane * 4] = acc; }
        __syncthreads();
        if (kh == 0) {
          float4v o4 = *(const float4v*)&S.red[bt * 256 + lane * 4];
#pragma unroll
          for (int r = 0; r < 4; r++) {
            const int b = bt * 16 + q * 4 + r;
            float v = ALPHAF * S.v2s[b * 17 + mr] + SCLF * (acc[r] + o4[r]);
            float z = v > 1.0f ? 1.0f : 0.0f;
            v -= z;
            S.v2s[b * 17 + mr] = v;
            out[O_L2SEQ + (b * TTT + u) * OUTT + o0 + mr] = z;
            float tr = DECAYF * S.l2trs[b * 17 + mr] + (1.f - DECAYF) * z;
            S.l2trs[b * 17 + mr] = tr;
            S.l2trT[swz64(mr, b)] = f2bf(tr);
          }
        }
        __syncthreads();   // l2trT ready; whb reads done before update writes

        {
          const short* l1ttg = (const short*)(ws + WS_L1TT) + ((p & 1) * CH + s) * (HIDD * BB);
#pragma unroll
          for (int j = 0; j < 16; j++) {
            const int htile = wv * 16 + j;
            float4v a2 = {0.f, 0.f, 0.f, 0.f};
#pragma unroll
            for (int ks = 0; ks < 2; ks++) {
              const int koff = ks * 32 + q * 8;
              short8v af = *(const short8v*)&S.l2trT[swz64(mr, koff)];
              short8v bf = *(const short8v*)(l1ttg + (htile * 16 + mr) * 64 + koff);
              a2 = __builtin_amdgcn_mfma_f32_16x16x32_bf16(af, bf, a2, 0, 0, 0);
            }
            const int hcol = htile * 16 + mr;
#pragma unroll
            for (int r = 0; r < 4; r++) {
              const int ol = q * 4 + r;
              float w = wreg[j * 4 + r] * (1.f - LRF * WDF) + (LRF / 64.f) * a2[r];
              wreg[j * 4 + r] = w;
              S.whb[swz2048(ol, hcol)] = f2bf(w);
            }
          }
        }
        __syncthreads();   // whb consistent before next step's gemm2
      }
      if (tid == 0) postflag(&FL2[p]);
    }
    for (int c = tid; c < 64 * 16; c += NTHR) {
      const int b = c >> 4, ol = c & 15;
      out[O_V2 + b * OUTT + o0 + ol] = S.v2s[b * 17 + ol];
      out[O_L2TR + b * OUTT + o0 + ol] = S.l2trs[b * 17 + ol];
    }
  }
}

extern "C" void kernel_launch(void* const* d_in, const int* in_sizes, int n_in,
                              void* d_out, int out_size, void* d_ws, size_t ws_size,
                              hipStream_t stream) {
  const float* x = (const float*)d_in[0];
  const float* w_in = (const float*)d_in[1];
  const float* w_hid = (const float*)d_in[2];
  float* out = (float*)d_out;
  char* ws = (char*)d_ws;

  void* args[] = {(void*)&x, (void*)&w_in, (void*)&w_hid, (void*)&out, (void*)&ws};
  hipLaunchCooperativeKernel(reinterpret_cast<void*>(kmain), dim3(NBLK), dim3(NTHR),
                             args, 0, stream);
}